// Round 1
// baseline (1991.703 us; speedup 1.0000x reference)
//
#include <hip/hip_runtime.h>
#include <hip/hip_bf16.h>

// ---------------------------------------------------------------------------
// Fused residual-MLP (N=65536, HID=512, NB=20) for gfx950.  Round 9.
//
// R8 post-mortem: MfmaUtil 35% at exactly the 19.4cyc/MFMA floor -> pipe idle
// 65%. One 1024-thr block/CU (h64+acc64=128 VGPR incl AGPR -> 4 waves/SIMD),
// phases serialize; GEMM phases bound by B-L2 stream (512KB/phase at ~25-30
// B/cyc eff) and A-LDS (1MB/phase: 16 waves x full A-tile).
// R9 = 8-wave geometry, same proven math/packing idea:
//  - 512 threads, wave owns 64 cols (4 interleaved 16-col tiles). A-LDS per
//    GEMM halves (8x amplification not 16x); per-wave MFMA doubles (256/GEMM)
//    so per-cycle B demand halves. ~200 VGPR < 256 cap (launch_bounds 512,2).
//  - phase A deleted: re-cast h->hn fused into epilogue2 (still 4 bar/iter).
//  - explicit depth-1 B prefetch in kc-loop + cross-barrier kc0 prefetch.
//  - per-block kc rotation (rot = blockIdx&15) de-aligns the identical L2
//    weight address streams across CUs (accumulate-order change only).
// LN-stats still interleaved into the GEMM kc-loop (now 8 chunks, j=tid&7).
// All LDS patterns re-audited: A-read / stats-read land 8 dwords/bank (data
// floor); epi uint2 writes 2-way (free).
// ---------------------------------------------------------------------------

typedef float  fvec4 __attribute__((ext_vector_type(4)));
typedef __bf16 bvec8 __attribute__((ext_vector_type(8)));

#define HN_STRIDE 520                 // ushorts per hn row (proven R1-R8)
#define WCHUNK    32768               // ushorts per (b,slot,w) chunk, w=0..7
#define SMEM_BYTES (64*HN_STRIDE*2 + 64*8)       // 66560 + 512 = 67072
#define WPK_USHORTS ((size_t)20*2*8*WCHUNK)      // 10,485,760 (same as R8)

__device__ __forceinline__ unsigned int f2bf(float v) {
    unsigned int u = __float_as_uint(v);
    return (u + 0x7fffu + ((u >> 16) & 1u)) >> 16;   // RNE to bf16
}
__device__ __forceinline__ unsigned int pkbf(float a, float b) {
    __hip_bfloat162 t = __float22bfloat162_rn(make_float2(a, b));
    unsigned int r;
    __builtin_memcpy(&r, &t, 4);                     // v_cvt_pk_bf16_f32
    return r;
}
__device__ __forceinline__ float silu_f(float v) {
    return v * (1.0f / (1.0f + __expf(-v)));
}

// ---- weight pre-pack: bf16(gamma_k * W[b][k][n]) in MFMA B-fragment order -
// chunk = w + 8*slot + 16*b ; within chunk: [kc][t][lane] x 16B
// col mapping: n = w*64 + (lane&15)*4 + t  (4 interleaved col-tiles per wave)
__global__ __launch_bounds__(256) void pack_weights(
        const float* __restrict__ w1, const float* __restrict__ w2,
        const float* __restrict__ g1, const float* __restrict__ g2,
        unsigned short* __restrict__ pk) {
    int tid = blockIdx.x * 256 + threadIdx.x;
    int l  = tid & 63;
    int f  = tid >> 6;
    int t  = f & 3;
    int kc = (f >> 2) & 15;
    int w  = (f >> 6) & 7;
    int g  = (f >> 9) & 1;
    int b  = f >> 10;
    const float* src = g ? w2 : w1;
    const float* gs  = (g ? g2 : g1) + b * 512;
    int k0 = kc * 32 + (l >> 4) * 8;
    int n  = w * 64 + (l & 15) * 4 + t;
    const float* s = src + ((size_t)b * 512 + k0) * 512 + n;
    unsigned int r[4];
#pragma unroll
    for (int j = 0; j < 4; ++j) {
        float ga = gs[k0 + 2 * j];
        float gb = gs[k0 + 2 * j + 1];
        unsigned int lo = f2bf(ga * s[(size_t)(2*j) * 512]);
        unsigned int hi = f2bf(gb * s[(size_t)(2*j + 1) * 512]);
        r[j] = lo | (hi << 16);
    }
    *(uint4*)(pk + (size_t)tid * 8) = make_uint4(r[0], r[1], r[2], r[3]);
}

// ---- u/vc precompute: u_n = sum_j g_j W_jn ; vc_n = sum_j beta_j W_jn + fcb_n
__global__ __launch_bounds__(512) void make_uv(
        const float* __restrict__ w1, const float* __restrict__ w2,
        const float* __restrict__ g1, const float* __restrict__ bl1,
        const float* __restrict__ cb1,
        const float* __restrict__ g2, const float* __restrict__ bl2,
        const float* __restrict__ cb2,
        float* __restrict__ uv) {
    int b = blockIdx.x >> 1, slot = blockIdx.x & 1, n = threadIdx.x;
    const float* W  = (slot ? w2 : w1) + (size_t)b * 512 * 512;
    const float* g  = (slot ? g2 : g1) + b * 512;
    const float* bl = (slot ? bl2 : bl1) + b * 512;
    const float* cb = (slot ? cb2 : cb1) + b * 512;
    float u = 0.f, v = 0.f;
    for (int j = 0; j < 512; ++j) {
        float wv = W[(size_t)j * 512 + n];
        u = fmaf(g[j], wv, u);
        v = fmaf(bl[j], wv, v);
    }
    uv[((b * 2 + slot) * 2 + 0) * 512 + n] = u;
    uv[((b * 2 + slot) * 2 + 1) * 512 + n] = v + cb[n];
}

__device__ __forceinline__ void acc_u32(unsigned int u, float& s, float& ss) {
    float lo = __uint_as_float(u << 16);
    float hi = __uint_as_float(u & 0xFFFF0000u);
    s += lo + hi;
    ss = __builtin_fmaf(lo, lo, ss);
    ss = __builtin_fmaf(hi, hi, ss);
}

// ---- GEMM (wave = 64 rows x 64 cols) with LN-stats reduce interleaved ------
// Stats of the CURRENT hn contents land in mv (visible after next barrier).
// kc order rotated per block (rot) to de-align L2 weight streams across CUs.
__device__ __forceinline__ void gemm_red(
        fvec4 acc[4][4], const unsigned short* hn,
        const unsigned short* __restrict__ wp, const uint4* pre,
        float2* mv, int l, int c, int q, int tid, int rot) {
    const uint4* wp4 = (const uint4*)wp;
    const int r = tid >> 3, j = tid & 7;
    float s = 0.f, ss = 0.f;
    uint4 bcur[4] = {pre[0], pre[1], pre[2], pre[3]};
#pragma unroll
    for (int it = 0; it < 16; ++it) {
        const int kc = (it + rot) & 15;
        uint4 bnxt[4];
        if (it < 15) {                       // depth-1 B prefetch
            const int kn = (kc + 1) & 15;
#pragma unroll
            for (int t = 0; t < 4; ++t) bnxt[t] = wp4[(kn * 4 + t) * 64 + l];
        }
        bvec8 a[4];
#pragma unroll
        for (int rb = 0; rb < 4; ++rb)
            a[rb] = *(const bvec8*)(hn + (rb * 16 + c) * HN_STRIDE + kc * 32 + q * 8);
        if (it >= 4 && it < 12) {   // 8 stats chunks hidden under the MFMA stream
            uint4 pv = *(const uint4*)(hn + r * HN_STRIDE + (j + 8 * (it - 4)) * 8);
            acc_u32(pv.x, s, ss); acc_u32(pv.y, s, ss);
            acc_u32(pv.z, s, ss); acc_u32(pv.w, s, ss);
        }
#pragma unroll
        for (int rb = 0; rb < 4; ++rb) {
#pragma unroll
            for (int t = 0; t < 4; ++t) {
                bvec8 bb;
                __builtin_memcpy(&bb, &bcur[t], 16);
                acc[rb][t] = __builtin_amdgcn_mfma_f32_16x16x32_bf16(a[rb], bb, acc[rb][t], 0, 0, 0);
            }
        }
        if (it < 15) {
#pragma unroll
            for (int t = 0; t < 4; ++t) bcur[t] = bnxt[t];
        }
    }
    s += __shfl_xor(s, 1); ss += __shfl_xor(ss, 1);
    s += __shfl_xor(s, 2); ss += __shfl_xor(ss, 2);
    s += __shfl_xor(s, 4); ss += __shfl_xor(ss, 4);
    if (j == 0) {
        float mean = s * (1.f / 512.f);
        float var  = ss * (1.f / 512.f) - mean * mean;
        mv[r] = make_float2(mean, rsqrtf(var + 1e-5f));
    }
}

// ---- standalone stats from hn (final LN), 512-thread version --------------
__device__ __forceinline__ void reduce_mv_hn(const unsigned short* hn,
                                             float2* mv, int tid) {
    int r = tid >> 3, j = tid & 7;
    float s = 0.f, ss = 0.f;
#pragma unroll
    for (int u = 0; u < 8; ++u) {
        uint4 pv = *(const uint4*)(hn + r * HN_STRIDE + (j + 8 * u) * 8);
        acc_u32(pv.x, s, ss); acc_u32(pv.y, s, ss);
        acc_u32(pv.z, s, ss); acc_u32(pv.w, s, ss);
    }
    s += __shfl_xor(s, 1); ss += __shfl_xor(ss, 1);
    s += __shfl_xor(s, 2); ss += __shfl_xor(ss, 2);
    s += __shfl_xor(s, 4); ss += __shfl_xor(ss, 4);
    if (j == 0) {
        float mean = s * (1.f / 512.f);
        float var  = ss * (1.f / 512.f) - mean * mean;
        mv[r] = make_float2(mean, rsqrtf(var + 1e-5f));
    }
}

__global__ __launch_bounds__(512, 2) void mlp_fused(
        const float* __restrict__ x,
        const float* __restrict__ in_w,  const float* __restrict__ in_b,
        const float* __restrict__ out_ln_g, const float* __restrict__ out_ln_b,
        const float* __restrict__ out_w, const float* __restrict__ out_b,
        const unsigned short* __restrict__ wpk,
        const float* __restrict__ uv,
        float* __restrict__ out) {
    extern __shared__ char smem[];
    unsigned short* hn = (unsigned short*)smem;                  // 66560 B
    float* hnf = (float*)smem;                                   // alias (final)
    float2* mv = (float2*)(smem + 64 * HN_STRIDE * 2);           //   512 B

    const int tid = threadIdx.x;
    const int w = tid >> 6;            // wave 0..7 -> cols [64w, 64w+64)
    const int l = tid & 63, c = l & 15, q = l >> 4;
    const int colbase = w * 64 + c * 4;
    const int row0 = blockIdx.x * 64;
    const int rot = blockIdx.x & 15;

    float h[4][4][4];   // [rb][i][t] : row rb*16+q*4+i, col colbase+t

    // ---- in-proj + SiLU + initial cast into hn ----
    {
        fvec4 iw0 = *(const fvec4*)(in_w + colbase);
        fvec4 iw1 = *(const fvec4*)(in_w + 512 + colbase);
        fvec4 ib  = *(const fvec4*)(in_b + colbase);
#pragma unroll
        for (int rb = 0; rb < 4; ++rb)
#pragma unroll
            for (int i = 0; i < 4; ++i) {
                int row = rb * 16 + q * 4 + i;
                float2 xv = *(const float2*)(x + (size_t)(row0 + row) * 2);
#pragma unroll
                for (int t = 0; t < 4; ++t)
                    h[rb][i][t] = silu_f(xv.x * iw0[t] + xv.y * iw1[t] + ib[t]);
                *(uint2*)(hn + row * HN_STRIDE + colbase) =
                    make_uint2(pkbf(h[rb][i][0], h[rb][i][1]),
                               pkbf(h[rb][i][2], h[rb][i][3]));
            }
    }

    for (int b = 0; b < 20; ++b) {
        const unsigned short* wp1 = wpk + (size_t)(b * 16 + w) * WCHUNK;
        const unsigned short* wp2 = wpk + (size_t)(b * 16 + 8 + w) * WCHUNK;
        fvec4 u1  = *(const fvec4*)(uv + ((b * 2 + 0) * 2 + 0) * 512 + colbase);
        fvec4 vc1 = *(const fvec4*)(uv + ((b * 2 + 0) * 2 + 1) * 512 + colbase);
        fvec4 u2  = *(const fvec4*)(uv + ((b * 2 + 1) * 2 + 0) * 512 + colbase);
        fvec4 vc2 = *(const fvec4*)(uv + ((b * 2 + 1) * 2 + 1) * 512 + colbase);

        // prefetch gemm1 first-kc B-frags, carried across bar1 in VGPRs
        uint4 pre[4];
#pragma unroll
        for (int t = 0; t < 4; ++t)
            pre[t] = ((const uint4*)wp1)[(rot * 4 + t) * 64 + l];
        __syncthreads();                               // bar1: hn(h) ready

        fvec4 acc[4][4];
#pragma unroll
        for (int rb = 0; rb < 4; ++rb)
#pragma unroll
            for (int t = 0; t < 4; ++t) acc[rb][t] = (fvec4){0.f, 0.f, 0.f, 0.f};
        gemm_red(acc, hn, wp1, pre, mv, l, c, q, tid, rot);
        __syncthreads();                               // bar2: mv1 ready, hn reads done

        // epilogue1: t = silu(inv*acc - inv*m*u1 + vc1) -> hn ; prefetch gemm2
#pragma unroll
        for (int t = 0; t < 4; ++t)
            pre[t] = ((const uint4*)wp2)[(rot * 4 + t) * 64 + l];
#pragma unroll
        for (int rb = 0; rb < 4; ++rb)
#pragma unroll
            for (int i = 0; i < 4; ++i) {
                int row = rb * 16 + q * 4 + i;
                float2 m = mv[row];
                float inv = m.y, minv = -m.x * m.y;
                float t0 = silu_f(__builtin_fmaf(acc[rb][0][i], inv,
                                  __builtin_fmaf(minv, u1[0], vc1[0])));
                float t1 = silu_f(__builtin_fmaf(acc[rb][1][i], inv,
                                  __builtin_fmaf(minv, u1[1], vc1[1])));
                float t2 = silu_f(__builtin_fmaf(acc[rb][2][i], inv,
                                  __builtin_fmaf(minv, u1[2], vc1[2])));
                float t3 = silu_f(__builtin_fmaf(acc[rb][3][i], inv,
                                  __builtin_fmaf(minv, u1[3], vc1[3])));
                *(uint2*)(hn + row * HN_STRIDE + colbase) =
                    make_uint2(pkbf(t0, t1), pkbf(t2, t3));
            }
        __syncthreads();                               // bar3: hn(t) ready

#pragma unroll
        for (int rb = 0; rb < 4; ++rb)
#pragma unroll
            for (int t = 0; t < 4; ++t) acc[rb][t] = (fvec4){0.f, 0.f, 0.f, 0.f};
        gemm_red(acc, hn, wp2, pre, mv, l, c, q, tid, rot);
        __syncthreads();                               // bar4: mv2 ready, hn reads done

        // epilogue2: h += inv*acc - inv*m*u2 + vc2 (fp32 residual) + fused
        // re-cast into hn for the next block's GEMM1 (phase A deleted)
#pragma unroll
        for (int rb = 0; rb < 4; ++rb)
#pragma unroll
            for (int i = 0; i < 4; ++i) {
                int row = rb * 16 + q * 4 + i;
                float2 m = mv[row];
                float inv = m.y, minv = -m.x * m.y;
#pragma unroll
                for (int t = 0; t < 4; ++t)
                    h[rb][i][t] = __builtin_fmaf(acc[rb][t][i], inv,
                        h[rb][i][t] + __builtin_fmaf(minv, u2[t], vc2[t]));
                *(uint2*)(hn + row * HN_STRIDE + colbase) =
                    make_uint2(pkbf(h[rb][i][0], h[rb][i][1]),
                               pkbf(h[rb][i][2], h[rb][i][3]));
            }
    }

    // ---- final LN + SiLU + out-proj ----
    __syncthreads();
    reduce_mv_hn(hn, mv, tid);
    __syncthreads();
    {
        fvec4 og = *(const fvec4*)(out_ln_g + colbase);
        fvec4 ob = *(const fvec4*)(out_ln_b + colbase);
        fvec4 ow = *(const fvec4*)(out_w + colbase);
        const int pcol = w * 16 + c;
#pragma unroll
        for (int rb = 0; rb < 4; ++rb)
#pragma unroll
            for (int i = 0; i < 4; ++i) {
                int row = rb * 16 + q * 4 + i;
                float2 m = mv[row];
                float sacc = 0.f;
#pragma unroll
                for (int t = 0; t < 4; ++t) {
                    float v = (h[rb][i][t] - m.x) * m.y * og[t] + ob[t];
                    sacc += silu_f(v) * ow[t];
                }
                hnf[pcol * 65 + row] = sacc;
            }
    }
    __syncthreads();
    {
        int r = tid >> 3, j = tid & 7;
        float s = 0.f;
#pragma unroll
        for (int u = 0; u < 16; ++u)
            s += hnf[(j + 8 * u) * 65 + r];
        s += __shfl_xor(s, 1);
        s += __shfl_xor(s, 2);
        s += __shfl_xor(s, 4);
        if (j == 0) out[row0 + r] = s + out_b[0];
    }
}

extern "C" void kernel_launch(void* const* d_in, const int* in_sizes, int n_in,
                              void* d_out, int out_size, void* d_ws, size_t ws_size,
                              hipStream_t stream) {
    const float* x        = (const float*)d_in[0];
    const float* in_w     = (const float*)d_in[1];
    const float* in_b     = (const float*)d_in[2];
    const float* ln1_g    = (const float*)d_in[3];
    const float* ln1_b    = (const float*)d_in[4];
    const float* fc1_w    = (const float*)d_in[5];
    const float* fc1_b    = (const float*)d_in[6];
    const float* ln2_g    = (const float*)d_in[7];
    const float* ln2_b    = (const float*)d_in[8];
    const float* fc2_w    = (const float*)d_in[9];
    const float* fc2_b    = (const float*)d_in[10];
    const float* out_ln_g = (const float*)d_in[11];
    const float* out_ln_b = (const float*)d_in[12];
    const float* out_w    = (const float*)d_in[13];
    const float* out_b    = (const float*)d_in[14];
    float* out = (float*)d_out;
    unsigned short* wpk = (unsigned short*)d_ws;            // 20,971,520 B
    float* uv = (float*)((char*)d_ws + WPK_USHORTS * 2);    //    163,840 B

    (void)hipFuncSetAttribute((const void*)mlp_fused,
                              hipFuncAttributeMaxDynamicSharedMemorySize, SMEM_BYTES);

    pack_weights<<<5120, 256, 0, stream>>>(fc1_w, fc2_w, ln1_g, ln2_g, wpk);
    make_uv<<<40, 512, 0, stream>>>(fc1_w, fc2_w, ln1_g, ln1_b, fc1_b,
                                    ln2_g, ln2_b, fc2_b, uv);
    mlp_fused<<<1024, 512, SMEM_BYTES, stream>>>(
        x, in_w, in_b, out_ln_g, out_ln_b, out_w, out_b, wpk, uv, out);
}